// Round 1
// baseline (4925.546 us; speedup 1.0000x reference)
//
#include <hip/hip_runtime.h>

constexpr int N = 100000;
constexpr int E = 1600000;

// out[row][m] = act( sum_i in[row][i]*W[m][i] + bias[m]
//                    (+ sum_i in2[row][i]*W2[m][i] if DUAL)
//                    (+ add[row][m] if add) )
// One row per thread; row cached in VGPRs; W/bias reads are wave-uniform
// (compiler scalarizes -> s_load broadcast), so the inner loop is ~pure FMA.
template<int K, int M, bool RELU, bool DUAL>
__global__ __launch_bounds__(256) void gemm_rows(
    const float* __restrict__ in, const float* __restrict__ W,
    const float* __restrict__ bias,
    const float* __restrict__ in2, const float* __restrict__ W2,
    const float* __restrict__ add,
    float* __restrict__ out)
{
    int row = blockIdx.x * 256 + threadIdx.x;
    if (row >= N) return;

    float a[K];
    {
        const float* ip = in + (size_t)row * K;
        #pragma unroll
        for (int i = 0; i < K; i += 4) {
            float4 v = *(const float4*)(ip + i);
            a[i] = v.x; a[i+1] = v.y; a[i+2] = v.z; a[i+3] = v.w;
        }
    }
    float a2[DUAL ? K : 4];
    if (DUAL) {
        const float* ip2 = in2 + (size_t)row * K;
        #pragma unroll
        for (int i = 0; i < K; i += 4) {
            float4 v = *(const float4*)(ip2 + i);
            a2[i] = v.x; a2[i+1] = v.y; a2[i+2] = v.z; a2[i+3] = v.w;
        }
    }

    float* op = out + (size_t)row * M;
    const float* ad = add ? add + (size_t)row * M : nullptr;

    #pragma unroll 1
    for (int mg = 0; mg < M / 4; ++mg) {
        float acc0, acc1, acc2, acc3;
        if (bias) {
            acc0 = bias[mg*4+0]; acc1 = bias[mg*4+1];
            acc2 = bias[mg*4+2]; acc3 = bias[mg*4+3];
        } else {
            acc0 = acc1 = acc2 = acc3 = 0.f;
        }
        if (ad) {
            float4 t = *(const float4*)(ad + mg*4);
            acc0 += t.x; acc1 += t.y; acc2 += t.z; acc3 += t.w;
        }
        {
            const float* w0 = W + (size_t)(mg*4+0) * K;
            const float* w1 = w0 + K;
            const float* w2 = w0 + 2*K;
            const float* w3 = w0 + 3*K;
            #pragma unroll
            for (int i = 0; i < K; ++i) {
                float av = a[i];
                acc0 = fmaf(av, w0[i], acc0);
                acc1 = fmaf(av, w1[i], acc1);
                acc2 = fmaf(av, w2[i], acc2);
                acc3 = fmaf(av, w3[i], acc3);
            }
        }
        if (DUAL) {
            const float* u0 = W2 + (size_t)(mg*4+0) * K;
            const float* u1 = u0 + K;
            const float* u2 = u0 + 2*K;
            const float* u3 = u0 + 3*K;
            #pragma unroll
            for (int i = 0; i < K; ++i) {
                float av = a2[i];
                acc0 = fmaf(av, u0[i], acc0);
                acc1 = fmaf(av, u1[i], acc1);
                acc2 = fmaf(av, u2[i], acc2);
                acc3 = fmaf(av, u3[i], acc3);
            }
        }
        if (RELU) {
            acc0 = fmaxf(acc0, 0.f); acc1 = fmaxf(acc1, 0.f);
            acc2 = fmaxf(acc2, 0.f); acc3 = fmaxf(acc3, 0.f);
        }
        float4 r; r.x = acc0; r.y = acc1; r.z = acc2; r.w = acc3;
        *(float4*)(op + mg*4) = r;
    }
}

// agg[dst] += feat[src] for every edge; thread per (edge, float4 group).
template<int C>
__global__ __launch_bounds__(256) void scatter_kernel(
    const float* __restrict__ feat, const int* __restrict__ ei,
    float* __restrict__ agg)
{
    constexpr int GP = C / 4;
    const int total = E * GP;
    for (int idx = blockIdx.x * 256 + threadIdx.x; idx < total;
         idx += gridDim.x * 256) {
        int e = idx / GP;
        int g = idx - e * GP;
        int s = ei[e];
        int d = ei[E + e];
        float4 v = *(const float4*)(feat + (size_t)s * C + g * 4);
        float* p = agg + (size_t)d * C + g * 4;
        atomicAdd(p + 0, v.x);
        atomicAdd(p + 1, v.y);
        atomicAdd(p + 2, v.z);
        atomicAdd(p + 3, v.w);
    }
}

extern "C" void kernel_launch(void* const* d_in, const int* in_sizes, int n_in,
                              void* d_out, int out_size, void* d_ws, size_t ws_size,
                              hipStream_t stream)
{
    const float* x   = (const float*)d_in[0];
    const int*   ei  = (const int*)d_in[1];
    const float *e1_Wp=(const float*)d_in[2],  *e1_bp=(const float*)d_in[3],
                *e1_Wl=(const float*)d_in[4],  *e1_bl=(const float*)d_in[5],
                *e1_Wr=(const float*)d_in[6];
    const float *e2_Wp=(const float*)d_in[7],  *e2_bp=(const float*)d_in[8],
                *e2_Wl=(const float*)d_in[9],  *e2_bl=(const float*)d_in[10],
                *e2_Wr=(const float*)d_in[11];
    const float *d1_Wp=(const float*)d_in[12], *d1_bp=(const float*)d_in[13],
                *d1_Wl=(const float*)d_in[14], *d1_bl=(const float*)d_in[15],
                *d1_Wr=(const float*)d_in[16];
    const float *d2_Wp=(const float*)d_in[17], *d2_bp=(const float*)d_in[18],
                *d2_Wl=(const float*)d_in[19], *d2_bl=(const float*)d_in[20],
                *d2_Wr=(const float*)d_in[21];

    float* A  = (float*)d_ws;             // [N][128] max
    float* B  = A  + (size_t)N * 128;     // [N][64] max (scatter target)
    float* C1 = B  + (size_t)N * 64;      // [N][128] inter-layer
    float* P  = C1 + (size_t)N * 128;     // [N][64] max (pre-transformed msgs)

    float* xrec = (float*)d_out;
    float* z    = (float*)d_out + (size_t)N * 64;

    const int GB = (N + 255) / 256;
    dim3 blk(256);

    // ---- conv1 (e1): 64 -> 128, relu(out) ----
    gemm_rows<64,64,true,false><<<GB, blk, 0, stream>>>(x, e1_Wp, e1_bp, nullptr, nullptr, nullptr, A);
    hipMemsetAsync(B, 0, (size_t)N * 64 * 4, stream);
    scatter_kernel<64><<<2048, blk, 0, stream>>>(A, ei, B);
    gemm_rows<64,128,true,true><<<GB, blk, 0, stream>>>(B, e1_Wl, e1_bl, x, e1_Wr, nullptr, C1);

    // ---- conv2 (e2): 128 -> 32, out = z (no relu) ----
    // scatter in the 32-dim: p = h @ Wl^T first (linearity of segment_sum)
    gemm_rows<128,128,true,false><<<GB, blk, 0, stream>>>(C1, e2_Wp, e2_bp, nullptr, nullptr, nullptr, A);
    gemm_rows<128,32,false,false><<<GB, blk, 0, stream>>>(A, e2_Wl, nullptr, nullptr, nullptr, nullptr, P);
    hipMemsetAsync(B, 0, (size_t)N * 32 * 4, stream);
    scatter_kernel<32><<<2048, blk, 0, stream>>>(P, ei, B);
    gemm_rows<128,32,false,false><<<GB, blk, 0, stream>>>(C1, e2_Wr, e2_bl, nullptr, nullptr, B, z);

    // ---- conv3 (d1): 32 -> 128, relu(out) ----
    gemm_rows<32,32,true,false><<<GB, blk, 0, stream>>>(z, d1_Wp, d1_bp, nullptr, nullptr, nullptr, A);
    hipMemsetAsync(B, 0, (size_t)N * 32 * 4, stream);
    scatter_kernel<32><<<2048, blk, 0, stream>>>(A, ei, B);
    gemm_rows<32,128,true,true><<<GB, blk, 0, stream>>>(B, d1_Wl, d1_bl, z, d1_Wr, nullptr, C1);

    // ---- conv4 (d2): 128 -> 64, out = x_rec (no relu) ----
    gemm_rows<128,128,true,false><<<GB, blk, 0, stream>>>(C1, d2_Wp, d2_bp, nullptr, nullptr, nullptr, A);
    gemm_rows<128,64,false,false><<<GB, blk, 0, stream>>>(A, d2_Wl, nullptr, nullptr, nullptr, nullptr, P);
    hipMemsetAsync(B, 0, (size_t)N * 64 * 4, stream);
    scatter_kernel<64><<<2048, blk, 0, stream>>>(P, ei, B);
    gemm_rows<128,64,false,false><<<GB, blk, 0, stream>>>(C1, d2_Wr, d2_bl, nullptr, nullptr, B, xrec);
}

// Round 2
// 1311.094 us; speedup vs baseline: 3.7568x; 3.7568x over previous
//
#include <hip/hip_runtime.h>

constexpr int N = 100000;
constexpr int E = 1600000;

// ================= CSR build (dst-major) =================
__global__ __launch_bounds__(256) void hist_kernel(const int* __restrict__ ei,
                                                   int* __restrict__ deg) {
    for (int e = blockIdx.x * 256 + threadIdx.x; e < E; e += gridDim.x * 256)
        atomicAdd(&deg[ei[E + e]], 1);
}

__global__ __launch_bounds__(256) void scan_block(const int* __restrict__ deg,
                                                  int* __restrict__ off,
                                                  int* __restrict__ bsum) {
    __shared__ int tmp[256];
    int i = blockIdx.x * 256 + threadIdx.x;
    int v = (i < N) ? deg[i] : 0;
    tmp[threadIdx.x] = v;
    __syncthreads();
    for (int d = 1; d < 256; d <<= 1) {
        int t = (threadIdx.x >= d) ? tmp[threadIdx.x - d] : 0;
        __syncthreads();
        tmp[threadIdx.x] += t;
        __syncthreads();
    }
    if (i < N) off[i] = tmp[threadIdx.x] - v;   // exclusive within block
    if (threadIdx.x == 255) bsum[blockIdx.x] = tmp[255];
}

__global__ void scan_bsum(int* __restrict__ bsum, int nb) {
    __shared__ int tmp[512];
    int t = threadIdx.x;
    if (t < nb) tmp[t] = bsum[t];
    __syncthreads();
    if (t == 0) {
        int acc = 0;
        for (int b = 0; b < nb; ++b) { int x = tmp[b]; tmp[b] = acc; acc += x; }
    }
    __syncthreads();
    if (t < nb) bsum[t] = tmp[t];
}

__global__ __launch_bounds__(256) void scan_add(int* __restrict__ off,
                                                const int* __restrict__ bsum,
                                                int* __restrict__ cursor) {
    int i = blockIdx.x * 256 + threadIdx.x;
    if (i < N) { int v = off[i] + bsum[blockIdx.x]; off[i] = v; cursor[i] = v; }
}

__global__ __launch_bounds__(256) void fill_kernel(const int* __restrict__ ei,
                                                   int* __restrict__ cursor,
                                                   int* __restrict__ csr) {
    for (int e = blockIdx.x * 256 + threadIdx.x; e < E; e += gridDim.x * 256) {
        int pos = atomicAdd(&cursor[ei[E + e]], 1);
        csr[pos] = ei[e];
    }
}

// ================= pull aggregation (no atomics) =================
// C/4 threads per node; each owns a float4 slice, loops neighbors, writes once.
template<int C>
__global__ __launch_bounds__(256) void pull_kernel(const float* __restrict__ feat,
                                                   const int* __restrict__ off,
                                                   const int* __restrict__ csr,
                                                   float* __restrict__ out) {
    constexpr int TPN = C / 4;
    int t = blockIdx.x * 256 + threadIdx.x;
    int n = t / TPN, g = t % TPN;
    if (n >= N) return;
    int beg = off[n];
    int end = (n == N - 1) ? E : off[n + 1];
    float4 acc = {0.f, 0.f, 0.f, 0.f};
    for (int j = beg; j < end; ++j) {
        int s = csr[j];
        float4 v = *(const float4*)(feat + (size_t)s * C + g * 4);
        acc.x += v.x; acc.y += v.y; acc.z += v.z; acc.w += v.w;
    }
    *(float4*)(out + (size_t)n * C + g * 4) = acc;
}

// ================= row-per-thread GEMMs =================
// out = act( in@W^T + bias (+ in2@W2^T if DUAL) (+ add) )
template<int K, int M, bool RELU, bool DUAL>
__global__ __launch_bounds__(256) void gemm_rows(
    const float* __restrict__ in, const float* __restrict__ W,
    const float* __restrict__ bias,
    const float* __restrict__ in2, const float* __restrict__ W2,
    const float* __restrict__ add,
    float* __restrict__ out)
{
    int row = blockIdx.x * 256 + threadIdx.x;
    if (row >= N) return;

    float a[K];
    {
        const float* ip = in + (size_t)row * K;
        #pragma unroll
        for (int i = 0; i < K; i += 4) {
            float4 v = *(const float4*)(ip + i);
            a[i] = v.x; a[i+1] = v.y; a[i+2] = v.z; a[i+3] = v.w;
        }
    }
    float a2[DUAL ? K : 4];
    if (DUAL) {
        const float* ip2 = in2 + (size_t)row * K;
        #pragma unroll
        for (int i = 0; i < K; i += 4) {
            float4 v = *(const float4*)(ip2 + i);
            a2[i] = v.x; a2[i+1] = v.y; a2[i+2] = v.z; a2[i+3] = v.w;
        }
    }

    float* op = out + (size_t)row * M;
    const float* ad = add ? add + (size_t)row * M : nullptr;

    #pragma unroll 1
    for (int mg = 0; mg < M / 4; ++mg) {
        float acc0, acc1, acc2, acc3;
        if (bias) {
            acc0 = bias[mg*4+0]; acc1 = bias[mg*4+1];
            acc2 = bias[mg*4+2]; acc3 = bias[mg*4+3];
        } else {
            acc0 = acc1 = acc2 = acc3 = 0.f;
        }
        if (ad) {
            float4 t = *(const float4*)(ad + mg*4);
            acc0 += t.x; acc1 += t.y; acc2 += t.z; acc3 += t.w;
        }
        {
            const float* w0 = W + (size_t)(mg*4+0) * K;
            const float* w1 = w0 + K;
            const float* w2 = w0 + 2*K;
            const float* w3 = w0 + 3*K;
            #pragma unroll
            for (int i = 0; i < K; ++i) {
                float av = a[i];
                acc0 = fmaf(av, w0[i], acc0);
                acc1 = fmaf(av, w1[i], acc1);
                acc2 = fmaf(av, w2[i], acc2);
                acc3 = fmaf(av, w3[i], acc3);
            }
        }
        if (DUAL) {
            const float* u0 = W2 + (size_t)(mg*4+0) * K;
            const float* u1 = u0 + K;
            const float* u2 = u0 + 2*K;
            const float* u3 = u0 + 3*K;
            #pragma unroll
            for (int i = 0; i < K; ++i) {
                float av = a2[i];
                acc0 = fmaf(av, u0[i], acc0);
                acc1 = fmaf(av, u1[i], acc1);
                acc2 = fmaf(av, u2[i], acc2);
                acc3 = fmaf(av, u3[i], acc3);
            }
        }
        if (RELU) {
            acc0 = fmaxf(acc0, 0.f); acc1 = fmaxf(acc1, 0.f);
            acc2 = fmaxf(acc2, 0.f); acc3 = fmaxf(acc3, 0.f);
        }
        float4 r; r.x = acc0; r.y = acc1; r.z = acc2; r.w = acc3;
        *(float4*)(op + mg*4) = r;
    }
}

// ================= fused projection + message pre-transform =================
// out[row] = relu(in[row]@Wp^T + bp) @ Wl^T   -- projected feats never hit memory
template<int K, int H, int M>
__global__ __launch_bounds__(256) void proj_mul(
    const float* __restrict__ in, const float* __restrict__ Wp,
    const float* __restrict__ bp, const float* __restrict__ Wl,
    float* __restrict__ out)
{
    int row = blockIdx.x * 256 + threadIdx.x;
    if (row >= N) return;
    float a[K];
    const float* ip = in + (size_t)row * K;
    #pragma unroll
    for (int i = 0; i < K; i += 4) {
        float4 v = *(const float4*)(ip + i);
        a[i] = v.x; a[i+1] = v.y; a[i+2] = v.z; a[i+3] = v.w;
    }
    float acc[M];
    #pragma unroll
    for (int g = 0; g < M; ++g) acc[g] = 0.f;

    #pragma unroll 1
    for (int mg = 0; mg < H / 4; ++mg) {
        float t0 = bp[mg*4+0], t1 = bp[mg*4+1], t2 = bp[mg*4+2], t3 = bp[mg*4+3];
        const float* w0 = Wp + (size_t)(mg*4) * K;
        const float* w1 = w0 + K;
        const float* w2 = w0 + 2*K;
        const float* w3 = w0 + 3*K;
        #pragma unroll
        for (int i = 0; i < K; ++i) {
            float av = a[i];
            t0 = fmaf(av, w0[i], t0);
            t1 = fmaf(av, w1[i], t1);
            t2 = fmaf(av, w2[i], t2);
            t3 = fmaf(av, w3[i], t3);
        }
        t0 = fmaxf(t0, 0.f); t1 = fmaxf(t1, 0.f);
        t2 = fmaxf(t2, 0.f); t3 = fmaxf(t3, 0.f);
        #pragma unroll
        for (int g = 0; g < M; ++g) {
            const float* wl = Wl + (size_t)g * H + mg*4;
            float s = fmaf(t0, wl[0], acc[g]);
            s = fmaf(t1, wl[1], s);
            s = fmaf(t2, wl[2], s);
            s = fmaf(t3, wl[3], s);
            acc[g] = s;
        }
    }
    float* op = out + (size_t)row * M;
    #pragma unroll
    for (int g = 0; g < M; g += 4) {
        float4 r; r.x = acc[g]; r.y = acc[g+1]; r.z = acc[g+2]; r.w = acc[g+3];
        *(float4*)(op + g) = r;
    }
}

extern "C" void kernel_launch(void* const* d_in, const int* in_sizes, int n_in,
                              void* d_out, int out_size, void* d_ws, size_t ws_size,
                              hipStream_t stream)
{
    const float* x   = (const float*)d_in[0];
    const int*   ei  = (const int*)d_in[1];
    const float *e1_Wp=(const float*)d_in[2],  *e1_bp=(const float*)d_in[3],
                *e1_Wl=(const float*)d_in[4],  *e1_bl=(const float*)d_in[5],
                *e1_Wr=(const float*)d_in[6];
    const float *e2_Wp=(const float*)d_in[7],  *e2_bp=(const float*)d_in[8],
                *e2_Wl=(const float*)d_in[9],  *e2_bl=(const float*)d_in[10],
                *e2_Wr=(const float*)d_in[11];
    const float *d1_Wp=(const float*)d_in[12], *d1_bp=(const float*)d_in[13],
                *d1_Wl=(const float*)d_in[14], *d1_bl=(const float*)d_in[15],
                *d1_Wr=(const float*)d_in[16];
    const float *d2_Wp=(const float*)d_in[17], *d2_bp=(const float*)d_in[18],
                *d2_Wl=(const float*)d_in[19], *d2_bl=(const float*)d_in[20],
                *d2_Wr=(const float*)d_in[21];

    // ---- workspace layout (ints first, 16B-aligned float regions) ----
    int* deg    = (int*)d_ws;           // N
    int* cursor = deg + N;              // N
    int* off    = cursor + N;           // N (+pad 16)
    int* bsum   = off + N + 16;         // 512
    int* csr    = bsum + 512;           // E
    float* C1   = (float*)(csr + E);    // N*128  layer output
    float* AP   = C1 + (size_t)N * 128; // N*64   projected / pre-transformed msgs
    float* B    = AP + (size_t)N * 64;  // N*64   aggregation result
    // total ≈ 110 MB

    float* xrec = (float*)d_out;
    float* z    = xrec + (size_t)N * 64;

    const int GB = (N + 255) / 256;     // 391 row-blocks
    const int SB = GB;

    // ---- CSR build (once; shared by all 4 convs) ----
    hipMemsetAsync(deg, 0, N * sizeof(int), stream);
    hist_kernel<<<2048, 256, 0, stream>>>(ei, deg);
    scan_block<<<SB, 256, 0, stream>>>(deg, off, bsum);
    scan_bsum<<<1, 512, 0, stream>>>(bsum, SB);
    scan_add<<<SB, 256, 0, stream>>>(off, bsum, cursor);
    fill_kernel<<<2048, 256, 0, stream>>>(ei, cursor, csr);

    // ---- conv1 (e1): 64 -> 128, relu ----
    gemm_rows<64,64,true,false><<<GB, 256, 0, stream>>>(x, e1_Wp, e1_bp, nullptr, nullptr, nullptr, AP);
    pull_kernel<64><<<(N*16 + 255)/256, 256, 0, stream>>>(AP, off, csr, B);
    gemm_rows<64,128,true,true><<<GB, 256, 0, stream>>>(B, e1_Wl, e1_bl, x, e1_Wr, nullptr, C1);

    // ---- conv2 (e2): 128 -> 32 = z (pre-transform msgs to 32-dim, fused) ----
    proj_mul<128,128,32><<<GB, 256, 0, stream>>>(C1, e2_Wp, e2_bp, e2_Wl, AP);
    pull_kernel<32><<<(N*8 + 255)/256, 256, 0, stream>>>(AP, off, csr, B);
    gemm_rows<128,32,false,false><<<GB, 256, 0, stream>>>(C1, e2_Wr, e2_bl, nullptr, nullptr, B, z);

    // ---- conv3 (d1): 32 -> 128, relu ----
    gemm_rows<32,32,true,false><<<GB, 256, 0, stream>>>(z, d1_Wp, d1_bp, nullptr, nullptr, nullptr, AP);
    pull_kernel<32><<<(N*8 + 255)/256, 256, 0, stream>>>(AP, off, csr, B);
    gemm_rows<32,128,true,true><<<GB, 256, 0, stream>>>(B, d1_Wl, d1_bl, z, d1_Wr, nullptr, C1);

    // ---- conv4 (d2): 128 -> 64 = x_rec (pre-transform msgs to 64-dim, fused) ----
    proj_mul<128,128,64><<<GB, 256, 0, stream>>>(C1, d2_Wp, d2_bp, d2_Wl, AP);
    pull_kernel<64><<<(N*16 + 255)/256, 256, 0, stream>>>(AP, off, csr, B);
    gemm_rows<128,64,false,false><<<GB, 256, 0, stream>>>(C1, d2_Wr, d2_bl, nullptr, nullptr, B, xrec);
}

// Round 3
// 1133.436 us; speedup vs baseline: 4.3457x; 1.1567x over previous
//
#include <hip/hip_runtime.h>

constexpr int N = 100000;
constexpr int E = 1600000;

// ================= CSR build (dst-major) =================
__global__ __launch_bounds__(256) void hist_kernel(const int* __restrict__ ei,
                                                   int* __restrict__ deg) {
    for (int e = blockIdx.x * 256 + threadIdx.x; e < E; e += gridDim.x * 256)
        atomicAdd(&deg[ei[E + e]], 1);
}

__global__ __launch_bounds__(256) void scan_block(const int* __restrict__ deg,
                                                  int* __restrict__ off,
                                                  int* __restrict__ bsum) {
    __shared__ int tmp[256];
    int i = blockIdx.x * 256 + threadIdx.x;
    int v = (i < N) ? deg[i] : 0;
    tmp[threadIdx.x] = v;
    __syncthreads();
    for (int d = 1; d < 256; d <<= 1) {
        int t = (threadIdx.x >= d) ? tmp[threadIdx.x - d] : 0;
        __syncthreads();
        tmp[threadIdx.x] += t;
        __syncthreads();
    }
    if (i < N) off[i] = tmp[threadIdx.x] - v;   // exclusive within block
    if (threadIdx.x == 255) bsum[blockIdx.x] = tmp[255];
}

__global__ void scan_bsum(int* __restrict__ bsum, int nb) {
    __shared__ int tmp[512];
    int t = threadIdx.x;
    if (t < nb) tmp[t] = bsum[t];
    __syncthreads();
    if (t == 0) {
        int acc = 0;
        for (int b = 0; b < nb; ++b) { int x = tmp[b]; tmp[b] = acc; acc += x; }
    }
    __syncthreads();
    if (t < nb) bsum[t] = tmp[t];
}

__global__ __launch_bounds__(256) void scan_add(int* __restrict__ off,
                                                const int* __restrict__ bsum,
                                                int* __restrict__ cursor) {
    int i = blockIdx.x * 256 + threadIdx.x;
    if (i < N) { int v = off[i] + bsum[blockIdx.x]; off[i] = v; cursor[i] = v; }
}

__global__ __launch_bounds__(256) void fill_kernel(const int* __restrict__ ei,
                                                   int* __restrict__ cursor,
                                                   int* __restrict__ csr) {
    for (int e = blockIdx.x * 256 + threadIdx.x; e < E; e += gridDim.x * 256) {
        int pos = atomicAdd(&cursor[ei[E + e]], 1);
        csr[pos] = ei[e];
    }
}

// ================= pull aggregation (no atomics) =================
// C/4 threads per node; each owns a float4 slice, loops neighbors, writes once.
// ADD: out[n] = agg[n] + out[n]  (partial result pre-written to out)
template<int C, bool ADD>
__global__ __launch_bounds__(256) void pull_kernel(const float* __restrict__ feat,
                                                   const int* __restrict__ off,
                                                   const int* __restrict__ csr,
                                                   float* __restrict__ out) {
    constexpr int TPN = C / 4;
    int t = blockIdx.x * 256 + threadIdx.x;
    int n = t / TPN, g = t % TPN;
    if (n >= N) return;
    int beg = off[n];
    int end = (n == N - 1) ? E : off[n + 1];
    float4 acc = {0.f, 0.f, 0.f, 0.f};
    for (int j = beg; j < end; ++j) {
        int s = csr[j];
        float4 v = *(const float4*)(feat + (size_t)s * C + g * 4);
        acc.x += v.x; acc.y += v.y; acc.z += v.z; acc.w += v.w;
    }
    float* op = out + (size_t)n * C + g * 4;
    if (ADD) {
        float4 b = *(const float4*)op;
        acc.x += b.x; acc.y += b.y; acc.z += b.z; acc.w += b.w;
    }
    *(float4*)op = acc;
}

// ================= M-split row-per-thread GEMM =================
// out[row][part*MC .. +MC] = act( in[row]@W^T + bias (+ in2[row]@W2^T) )
// part = blockIdx % SPLIT is block-uniform -> weight reads stay s_load broadcast.
template<int K, int M, int SPLIT, bool RELU, bool DUAL>
__global__ __launch_bounds__(256) void gemm_rows(
    const float* __restrict__ in, const float* __restrict__ W,
    const float* __restrict__ bias,
    const float* __restrict__ in2, const float* __restrict__ W2,
    float* __restrict__ out)
{
    constexpr int MC = M / SPLIT;
    const int part = blockIdx.x % SPLIT;
    const int row  = (blockIdx.x / SPLIT) * 256 + threadIdx.x;
    if (row >= N) return;

    float a[K];
    {
        const float* ip = in + (size_t)row * K;
        #pragma unroll
        for (int i = 0; i < K; i += 4) {
            float4 v = *(const float4*)(ip + i);
            a[i] = v.x; a[i+1] = v.y; a[i+2] = v.z; a[i+3] = v.w;
        }
    }
    float a2[DUAL ? K : 4];
    if (DUAL) {
        const float* ip2 = in2 + (size_t)row * K;
        #pragma unroll
        for (int i = 0; i < K; i += 4) {
            float4 v = *(const float4*)(ip2 + i);
            a2[i] = v.x; a2[i+1] = v.y; a2[i+2] = v.z; a2[i+3] = v.w;
        }
    }

    const float* Wb  = W + (size_t)part * MC * K;
    const float* W2b = DUAL ? W2 + (size_t)part * MC * K : nullptr;
    const float* bb  = bias ? bias + part * MC : nullptr;
    float* op = out + (size_t)row * M + part * MC;

    #pragma unroll 1
    for (int mg = 0; mg < MC / 4; ++mg) {
        float acc0, acc1, acc2, acc3;
        if (bb) {
            acc0 = bb[mg*4+0]; acc1 = bb[mg*4+1];
            acc2 = bb[mg*4+2]; acc3 = bb[mg*4+3];
        } else {
            acc0 = acc1 = acc2 = acc3 = 0.f;
        }
        {
            const float* w0 = Wb + (size_t)(mg*4+0) * K;
            const float* w1 = w0 + K;
            const float* w2 = w0 + 2*K;
            const float* w3 = w0 + 3*K;
            #pragma unroll
            for (int i = 0; i < K; ++i) {
                float av = a[i];
                acc0 = fmaf(av, w0[i], acc0);
                acc1 = fmaf(av, w1[i], acc1);
                acc2 = fmaf(av, w2[i], acc2);
                acc3 = fmaf(av, w3[i], acc3);
            }
        }
        if (DUAL) {
            const float* u0 = W2b + (size_t)(mg*4+0) * K;
            const float* u1 = u0 + K;
            const float* u2 = u0 + 2*K;
            const float* u3 = u0 + 3*K;
            #pragma unroll
            for (int i = 0; i < K; ++i) {
                float av = a2[i];
                acc0 = fmaf(av, u0[i], acc0);
                acc1 = fmaf(av, u1[i], acc1);
                acc2 = fmaf(av, u2[i], acc2);
                acc3 = fmaf(av, u3[i], acc3);
            }
        }
        if (RELU) {
            acc0 = fmaxf(acc0, 0.f); acc1 = fmaxf(acc1, 0.f);
            acc2 = fmaxf(acc2, 0.f); acc3 = fmaxf(acc3, 0.f);
        }
        float4 r; r.x = acc0; r.y = acc1; r.z = acc2; r.w = acc3;
        *(float4*)(op + mg*4) = r;
    }
}

extern "C" void kernel_launch(void* const* d_in, const int* in_sizes, int n_in,
                              void* d_out, int out_size, void* d_ws, size_t ws_size,
                              hipStream_t stream)
{
    const float* x   = (const float*)d_in[0];
    const int*   ei  = (const int*)d_in[1];
    const float *e1_Wp=(const float*)d_in[2],  *e1_bp=(const float*)d_in[3],
                *e1_Wl=(const float*)d_in[4],  *e1_bl=(const float*)d_in[5],
                *e1_Wr=(const float*)d_in[6];
    const float *e2_Wp=(const float*)d_in[7],  *e2_bp=(const float*)d_in[8],
                *e2_Wl=(const float*)d_in[9],  *e2_bl=(const float*)d_in[10],
                *e2_Wr=(const float*)d_in[11];
    const float *d1_Wp=(const float*)d_in[12], *d1_bp=(const float*)d_in[13],
                *d1_Wl=(const float*)d_in[14], *d1_bl=(const float*)d_in[15],
                *d1_Wr=(const float*)d_in[16];
    const float *d2_Wp=(const float*)d_in[17], *d2_bp=(const float*)d_in[18],
                *d2_Wl=(const float*)d_in[19], *d2_bl=(const float*)d_in[20],
                *d2_Wr=(const float*)d_in[21];

    // ---- workspace: off(N) + csr(E) ints, then 3 float regions (320N = 128MB)
    int* off  = (int*)d_ws;                     // N (persistent)
    int* csr  = off + N;                        // E (persistent)
    float* R1 = (float*)(csr + E);              // [N][128]  C1 (layer output)
    float* R2 = R1 + (size_t)N * 128;           // [N][128]  H / conv1 scratch
    float* R3 = R2 + (size_t)N * 128;           // [N][64]   AP / B
    // CSR-build temporaries alias R3 (build finishes before R3's first float use)
    int* deg    = (int*)R3;                     // N
    int* cursor = deg + N;                      // N
    int* bsum   = cursor + N;                   // 512

    float* xrec = (float*)d_out;                // [N][64]
    float* z    = xrec + (size_t)N * 64;        // [N][32]

    const int GB = (N + 255) / 256;             // 391

    // ---- CSR build (once; shared by all 4 convs) ----
    hipMemsetAsync(deg, 0, N * sizeof(int), stream);
    hist_kernel<<<2048, 256, 0, stream>>>(ei, deg);
    scan_block<<<GB, 256, 0, stream>>>(deg, off, bsum);
    scan_bsum<<<1, 512, 0, stream>>>(bsum, GB);
    scan_add<<<GB, 256, 0, stream>>>(off, bsum, cursor);
    fill_kernel<<<2048, 256, 0, stream>>>(ei, cursor, csr);

    float* AP1 = R2;                    // conv1 projected feats [N][64]
    float* B1  = R2 + (size_t)N * 64;   // conv1 agg [N][64]
    float* AP2 = R3;                    // conv2 pre-transformed msgs [N][32]
    float* B3  = R3 + (size_t)N * 32;   // conv3 agg [N][32]

    // ---- conv1 (e1): 64 -> 128, relu ----
    gemm_rows<64,64,4,true,false><<<GB*4, 256, 0, stream>>>(x, e1_Wp, e1_bp, nullptr, nullptr, AP1);
    pull_kernel<64,false><<<(N*16 + 255)/256, 256, 0, stream>>>(AP1, off, csr, B1);
    gemm_rows<64,128,4,true,true><<<GB*4, 256, 0, stream>>>(B1, e1_Wl, e1_bl, x, e1_Wr, R1);

    // ---- conv2 (e2): 128 -> 32 = z ----
    gemm_rows<128,32,4,false,false><<<GB*4, 256, 0, stream>>>(R1, e2_Wr, e2_bl, nullptr, nullptr, z);
    gemm_rows<128,128,4,true,false><<<GB*4, 256, 0, stream>>>(R1, e2_Wp, e2_bp, nullptr, nullptr, R2);
    gemm_rows<128,32,4,false,false><<<GB*4, 256, 0, stream>>>(R2, e2_Wl, nullptr, nullptr, nullptr, AP2);
    pull_kernel<32,true><<<(N*8 + 255)/256, 256, 0, stream>>>(AP2, off, csr, z);

    // ---- conv3 (d1): 32 -> 128, relu ----
    gemm_rows<32,32,2,true,false><<<GB*2, 256, 0, stream>>>(z, d1_Wp, d1_bp, nullptr, nullptr, AP2);
    pull_kernel<32,false><<<(N*8 + 255)/256, 256, 0, stream>>>(AP2, off, csr, B3);
    gemm_rows<32,128,4,true,true><<<GB*4, 256, 0, stream>>>(B3, d1_Wl, d1_bl, z, d1_Wr, R1);

    // ---- conv4 (d2): 128 -> 64 = x_rec ----
    gemm_rows<128,64,4,false,false><<<GB*4, 256, 0, stream>>>(R1, d2_Wr, d2_bl, nullptr, nullptr, xrec);
    gemm_rows<128,128,4,true,false><<<GB*4, 256, 0, stream>>>(R1, d2_Wp, d2_bp, nullptr, nullptr, R2);
    gemm_rows<128,64,4,false,false><<<GB*4, 256, 0, stream>>>(R2, d2_Wl, nullptr, nullptr, nullptr, R3);
    pull_kernel<64,true><<<(N*16 + 255)/256, 256, 0, stream>>>(R3, off, csr, xrec);
}